// Round 8
// baseline (191.404 us; speedup 1.0000x reference)
//
#include <hip/hip_runtime.h>

constexpr int S = 4096, M = 512, E = 16, CC = 128;
constexpr int H1 = 500, H2 = 500, H3 = 2000;

// fused: select = x@Wr^T + noise; top2; sel0 output; per-block column partials; zero counter
__global__ void k_route(const float* __restrict__ x, const float* __restrict__ noise,
                        const float* __restrict__ Wr, int* __restrict__ i0, int* __restrict__ i1,
                        float* __restrict__ g0, float* __restrict__ g1,
                        float* __restrict__ sel0, float* __restrict__ selpart,
                        int* __restrict__ counters) {
  if (blockIdx.x == 0 && threadIdx.x == 0) { counters[0] = 0; }
  int wid = threadIdx.x >> 6, lane = threadIdx.x & 63;
  int s = blockIdx.x * 4 + wid;
  const float* xr = x + (size_t)s * M;
  float xv[8];
#pragma unroll
  for (int c = 0; c < 8; ++c) xv[c] = xr[lane + 64 * c];
  float v[E];
#pragma unroll
  for (int e = 0; e < E; ++e) {
    const float* wr = Wr + (size_t)e * M;
    float acc = 0.f;
#pragma unroll
    for (int c = 0; c < 8; ++c) acc = fmaf(xv[c], wr[lane + 64 * c], acc);
#pragma unroll
    for (int off = 32; off; off >>= 1) acc += __shfl_xor(acc, off);
    v[e] = acc + noise[s * E + e];
  }
  int a0 = 0; float m0 = v[0];
#pragma unroll
  for (int e = 1; e < E; ++e) if (v[e] > m0) { m0 = v[e]; a0 = e; }
  int a1 = -1; float m1 = -3.4e38f;
#pragma unroll
  for (int e = 0; e < E; ++e) if (e != a0 && v[e] > m1) { m1 = v[e]; a1 = e; }
  __shared__ float vsh[4][16];
  if (lane < 16) vsh[wid][lane] = v[lane];
  if (lane == 0) { i0[s] = a0; i1[s] = a1; g0[s] = m0; g1[s] = m1; }
  if (lane < 16) {
    int e = lane;
    sel0[(size_t)s * 32 + e * 2 + 0] = (e == a0 && m0 != 0.f) ? 1.f : 0.f;
    sel0[(size_t)s * 32 + e * 2 + 1] = (e == a1 && m1 != 0.f) ? 1.f : 0.f;
  }
  __syncthreads();
  if (threadIdx.x < 16) {
    int e = threadIdx.x;
    selpart[blockIdx.x * 16 + e] = vsh[0][e] + vsh[1][e] + vsh[2][e] + vsh[3][e];
  }
}

// fused lists+gather+reduce: block=(ek,chunk); 8 groups of 128 threads scan 512-token segments
__global__ __launch_bounds__(1024) void k_gather(const float* __restrict__ x,
                        const int* __restrict__ i0, const int* __restrict__ i1,
                        const float* __restrict__ g0, const float* __restrict__ g1,
                        float* __restrict__ ei) {
  __shared__ int rsi[S];
  __shared__ float rsg[S];
  __shared__ float gacc[8][128];
  int b = blockIdx.x;                 // 128 = ek*4 + chunk
  int chunk = b & 3, ek = b >> 2;
  int k = ek & 1, e = ek >> 1;
  const int* route = k ? i1 : i0;
  const float* gg = k ? g1 : g0;
  int t = threadIdx.x;
  for (int i = t; i < S; i += 1024) { rsi[i] = route[i]; rsg[i] = gg[i]; }
  __syncthreads();
  int g = t >> 7, dl = t & 127;
  int d = chunk * 128 + dl;
  float acc = 0.f;
  int q0 = g * 512;
  for (int q = q0; q < q0 + 512; ++q) {
    if (rsi[q] == e && rsg[q] != 0.f) acc += x[(size_t)q * M + d];
  }
  gacc[g][dl] = acc;
  __syncthreads();
  if (t < 128) {
    float ssum = 0.f;
#pragma unroll
    for (int g2 = 0; g2 < 8; ++g2) ssum += gacc[g2][t];
    ei[ek * M + chunk * 128 + t] = ssum;
  }
}

// generic MLP layer: wave per (e,h) output neuron, both k rows at once
template <int DIN, int HOUT, bool RELU>
__global__ void k_layer(const float* __restrict__ in, const float* __restrict__ W,
                        const float* __restrict__ bias, float* __restrict__ out) {
  int w = (blockIdx.x * blockDim.x + threadIdx.x) >> 6;
  int lane = threadIdx.x & 63;
  if (w >= E * HOUT) return;
  int e = w / HOUT, h = w - e * HOUT;
  const float* wr = W + ((size_t)e * HOUT + h) * DIN;
  const float* in0 = in + (size_t)(e * 2 + 0) * DIN;
  const float* in1 = in + (size_t)(e * 2 + 1) * DIN;
  float a0 = 0.f, a1 = 0.f;
  for (int m = lane; m < DIN; m += 64) {
    float wv = wr[m];
    a0 += wv * in0[m];
    a1 += wv * in1[m];
  }
#pragma unroll
  for (int off = 32; off; off >>= 1) {
    a0 += __shfl_xor(a0, off);
    a1 += __shfl_xor(a1, off);
  }
  if (lane == 0) {
    float bb = bias[e * HOUT + h];
    float o0 = a0 + bb, o1 = a1 + bb;
    if (RELU) { o0 = fmaxf(o0, 0.f); o1 = fmaxf(o1, 0.f); }
    out[(size_t)(e * 2 + 0) * HOUT + h] = o0;
    out[(size_t)(e * 2 + 1) * HOUT + h] = o1;
  }
}

// gprep: block 0 = Gram32 + balance; blocks 1.. = row scalars + per-ek w/w2/count partials
__global__ __launch_bounds__(256) void k_gprep(const float* __restrict__ eo,
                        const float* __restrict__ selpart,
                        const int* __restrict__ idx1, const int* __restrict__ idx2,
                        const int* __restrict__ i0, const int* __restrict__ i1,
                        const float* __restrict__ g0, const float* __restrict__ g1,
                        float* __restrict__ G32, float* __restrict__ rowg,
                        int* __restrict__ rowe, float* __restrict__ wpart,
                        int* __restrict__ cpart,
                        float* __restrict__ outb, int ns, int ncnt, int npad) {
  int t = threadIdx.x;
  if (blockIdx.x == 0) {
    __shared__ float Es[32 * 132];
    __shared__ double red_d[256];
    __shared__ float dpl[16];
    for (int i = t; i < 32 * 128; i += 256) Es[(i >> 7) * 132 + (i & 127)] = eo[i];
    __syncthreads();
    for (int p = t; p < 1024; p += 256) {
      int u = p >> 5, v = p & 31;
      float s = 0.f;
#pragma unroll 8
      for (int d = 0; d < 128; ++d) s = fmaf(Es[u * 132 + d], Es[v * 132 + d], s);
      G32[p] = s;
    }
    // balance loss
    int e2 = t & 15, r0 = t >> 4;
    double acc = 0.0;
    for (int b2 = r0; b2 < 1024; b2 += 16) acc += (double)selpart[b2 * 16 + e2];
    red_d[t] = acc;
    __syncthreads();
    for (int off = 128; off >= 16; off >>= 1) { if (t < off) red_d[t] += red_d[t + off]; __syncthreads(); }
    if (t < 16) dpl[t] = (float)(red_d[t] / (double)S);
    __syncthreads();
    double acc2 = 0.0;
    for (int s2 = t; s2 < S; s2 += 256) acc2 += 0.5 * ((double)dpl[i0[s2]] + (double)dpl[i1[s2]]);
    red_d[t] = acc2;
    __syncthreads();
    for (int off = 128; off; off >>= 1) { if (t < off) red_d[t] += red_d[t + off]; __syncthreads(); }
    if (t == 0) outb[0] = (float)(red_d[0] / 256.0);
    return;
  }
  // rows blocks: 1 row per thread
  int blk = blockIdx.x - 1;
  int r = blk * 256 + t;
  float g = 0.f; int ek = 0;
  bool valid = (r < npad);
  if (r < ns)        { int tk = idx1[r];      ek = i0[tk] * 2 + 0; g = g0[tk]; }
  else if (r < ncnt) { int tk = idx2[r - ns]; ek = i1[tk] * 2 + 1; g = g1[tk]; }
  if (valid) { rowg[r] = g; rowe[r] = ek; }
  int ekb = valid ? ek : -1;
  __shared__ float sw[4][32], sw2[4][32];
  __shared__ int sc[4][32];
  int lane = t & 63, w = t >> 6;
  float g2 = g * g;
  for (int e = 0; e < 32; ++e) {
    unsigned long long m = __ballot(ekb == e);
    float vw = (ekb == e) ? g : 0.f;
    float vw2 = (ekb == e) ? g2 : 0.f;
#pragma unroll
    for (int off = 32; off; off >>= 1) { vw += __shfl_xor(vw, off); vw2 += __shfl_xor(vw2, off); }
    if (lane == 0) { sw[w][e] = vw; sw2[w][e] = vw2; sc[w][e] = __popcll(m); }
  }
  __syncthreads();
  if (t < 32) {
    wpart[blk * 64 + t]      = sw[0][t] + sw[1][t] + sw[2][t] + sw[3][t];
    wpart[blk * 64 + 32 + t] = sw2[0][t] + sw2[1][t] + sw2[2][t] + sw2[3][t];
    cpart[blk * 32 + t]      = sc[0][t] + sc[1][t] + sc[2][t] + sc[3][t];
  }
}

// mid: per-block expert-sort of 256 rows (deterministic counting sort) + cl compute
__global__ __launch_bounds__(256) void k_mid(const float* __restrict__ G32,
                        const float* __restrict__ wpart, const int* __restrict__ cpart,
                        const float* __restrict__ rowg, const int* __restrict__ rowe,
                        float* __restrict__ srowg, float* __restrict__ srowA,
                        int* __restrict__ srowe, float* __restrict__ srowsg,
                        float* __restrict__ cl2,
                        int ns, int ncnt, int npad, int nrowblk) {
  __shared__ int cpl[32 * 32];        // up to 32 row-blocks
  __shared__ int base[33];
  __shared__ int offmy[32];
  __shared__ float wf[32], w2f[32];
  __shared__ double redd[256];
  __shared__ int wcnt[4][32];
  __shared__ float c_sh;
  int t = threadIdx.x, blk = blockIdx.x;
  for (int i = t; i < nrowblk * 32; i += 256) cpl[i] = cpart[i];
  if (t < 32) {
    float sw = 0.f, sw2 = 0.f;
    for (int b = 0; b < nrowblk; ++b) { sw += wpart[b * 64 + t]; sw2 += wpart[b * 64 + 32 + t]; }
    wf[t] = sw; w2f[t] = sw2;
  }
  __syncthreads();
  if (t == 0) {
    int acc = 0;
    for (int e = 0; e < 32; ++e) {
      base[e] = acc;
      int tot = 0;
      for (int b = 0; b < nrowblk; ++b) tot += cpl[b * 32 + e];
      acc += tot;
    }
  }
  __syncthreads();
  if (t < 32) {
    int off = base[t];
    for (int b = 0; b < blk; ++b) off += cpl[b * 32 + t];
    offmy[t] = off;
  }
  // c = 1/(bw*16)  (identical in every block; block 0 publishes)
  double part = 0.0;
  for (int i = t; i < 1024; i += 256)
    part += (double)wf[i >> 5] * (double)wf[i & 31] * (double)G32[i];
  redd[t] = part;
  __syncthreads();
  for (int off = 128; off; off >>= 1) { if (t < off) redd[t] += redd[t + off]; __syncthreads(); }
  double wGw = redd[0];
  __syncthreads();
  redd[t] = (t < 32) ? (double)w2f[t] * (double)G32[t * 33] : 0.0;
  __syncthreads();
  for (int off = 128; off; off >>= 1) { if (t < off) redd[t] += redd[t + off]; __syncthreads(); }
  if (t == 0) {
    double nn = (double)ncnt;
    double sumd2 = 2.0 * nn * redd[0] - 2.0 * wGw;
    double bw = sumd2 / (nn * nn - nn) / 4.0;
    c_sh = (float)(1.0 / (bw * 16.0));
    if (blk == 0) cl2[0] = c_sh;
  }
  __syncthreads();
  float c = c_sh;
  // permutation of my 256 rows (stable by construction: lane order within wave, wave order)
  int r = blk * 256 + t;
  bool valid = (r < npad);
  float g = valid ? rowg[r] : 0.f;
  int ek = valid ? rowe[r] : -1;
  float sg = (r < ns) ? 1.f : (r < ncnt ? -1.f : 0.f);
  int lane = t & 63, w = t >> 6;
  int myrank = 0;
  for (int e = 0; e < 32; ++e) {
    unsigned long long m = __ballot(ek == e);
    if (ek == e) myrank = __popcll(m & ((1ull << lane) - 1ull));
    if (lane == 0) wcnt[w][e] = __popcll(m);
  }
  __syncthreads();
  if (valid) {
    int woff = 0;
    for (int w2 = 0; w2 < w; ++w2) woff += wcnt[w2][ek];
    int dest = offmy[ek] + woff + myrank;
    srowg[dest] = g;
    srowsg[dest] = sg;
    srowe[dest] = ek;
    srowA[dest] = c * g * g * G32[ek * 33];
  }
}

// tail: blocks [0,ntri) = mmd tiles on sorted rows; blocks [ntri,+2048) = token output;
//       last mmd block = final reduce
__global__ __launch_bounds__(256) void k_tail(const float* __restrict__ eo,
                      const int* __restrict__ i0, const int* __restrict__ i1,
                      const float* __restrict__ g0, const float* __restrict__ g1,
                      float* __restrict__ out,
                      const float* __restrict__ srowg, const float* __restrict__ srowA,
                      const int* __restrict__ srowe, const float* __restrict__ srowsg,
                      const float* __restrict__ G32, const float* __restrict__ cl2,
                      double* __restrict__ bsum, float* __restrict__ out_dist,
                      int ns, int ncnt, int nt, int ntri, int* __restrict__ counters) {
  int b = blockIdx.x, tid = threadIdx.x;
  if (b >= ntri) {
    int idx = (b - ntri) * 256 + tid;
    int s = idx >> 7, d = idx & (CC - 1);
    out[idx] = g0[s] * eo[(i0[s] * 2 + 0) * CC + d] + g1[s] * eo[(i1[s] * 2 + 1) * CC + d];
    return;
  }
  __shared__ float K2[32 * 33];
  __shared__ float gAs[136], aAs[136], gBs[136], aBs[136], sAs[136], sBs[136];
  __shared__ int eAs[136], eBs[136];
  __shared__ float wred[4];
  __shared__ double redd[256];
  __shared__ int lastflag;

  int L = b;
  int bi = 0, rem = L;
  while (rem >= nt - bi) { rem -= nt - bi; ++bi; }
  int bj = bi + rem;
  const int ib = bi * 128, jb = bj * 128;

  float c = cl2[0];
  for (int i = tid; i < 1024; i += 256) K2[(i >> 5) * 33 + (i & 31)] = 2.f * c * G32[i];
  if (tid < 128) {
    int p = (tid & 7) * 17 + (tid >> 3);
    gAs[p] = srowg[ib + tid]; aAs[p] = srowA[ib + tid];
    eAs[p] = srowe[ib + tid] * 33; sAs[p] = srowsg[ib + tid];
    gBs[p] = srowg[jb + tid]; aBs[p] = srowA[jb + tid];
    eBs[p] = srowe[jb + tid]; sBs[p] = srowsg[jb + tid];
  }
  __syncthreads();

  int ti = tid & 15, tj = tid >> 4;
  float gi[8], Ai[8], sgi[8], gj[8], Aj[8], sgj[8];
  int ei[8], ej[8];
#pragma unroll
  for (int r = 0; r < 8; ++r) {
    int p = r * 17 + ti;
    gi[r] = gAs[p]; Ai[r] = aAs[p]; ei[r] = eAs[p]; sgi[r] = sAs[p];
    int q = r * 17 + tj;
    gj[r] = gBs[q]; Aj[r] = aBs[q]; ej[r] = eBs[q]; sgj[r] = sBs[q];
  }

  float tsum = 0.f;
#pragma unroll
  for (int r = 0; r < 8; ++r) {
#pragma unroll
    for (int q = 0; q < 8; ++q) {
      float gg = gi[r] * gj[q];
      float arg = fmaf(K2[ei[r] + ej[q]], gg, -(Ai[r] + Aj[q]));
      float t = __expf(arg);
      float t2 = t * t;   float s5 = t + t2;
      float t4 = t2 * t2; s5 += t4;
      float t8 = t4 * t4; s5 += t8;
      float t16 = t8 * t8; s5 += t16;
      tsum = fmaf(sgi[r] * sgj[q], s5, tsum);
    }
  }
#pragma unroll
  for (int off = 32; off; off >>= 1) tsum += __shfl_xor(tsum, off);
  if ((tid & 63) == 0) wred[tid >> 6] = tsum;
  __syncthreads();
  if (tid == 0)
    bsum[L] = (double)(wred[0] + wred[1] + wred[2] + wred[3]) * ((bi == bj) ? 1.0 : 2.0);

  // last-mmd-block election -> final reduce (fixed order, deterministic)
  if (tid == 0) {
    __threadfence();
    int old = atomicAdd(&counters[0], 1);
    lastflag = (old == ntri - 1) ? 1 : 0;
  }
  __syncthreads();
  if (!lastflag) return;
  __threadfence();
  double acc = 0.0;
  for (int i = tid; i < ntri; i += 256) acc += bsum[i];
  redd[tid] = acc;
  __syncthreads();
  for (int off = 128; off; off >>= 1) { if (tid < off) redd[tid] += redd[tid + off]; __syncthreads(); }
  if (tid == 0) out_dist[0] = (float)(-redd[0] / ((double)ns * (double)ns));
}

extern "C" void kernel_launch(void* const* d_in, const int* in_sizes, int n_in,
                              void* d_out, int out_size, void* d_ws, size_t ws_size,
                              hipStream_t stream) {
  const float* x  = (const float*)d_in[0];
  const float* noise = (const float*)d_in[1];
  const float* Wr = (const float*)d_in[2];
  const float* W1 = (const float*)d_in[3];
  const float* b1 = (const float*)d_in[4];
  const float* W2 = (const float*)d_in[5];
  const float* b2 = (const float*)d_in[6];
  const float* W3 = (const float*)d_in[7];
  const float* b3 = (const float*)d_in[8];
  const float* W4 = (const float*)d_in[9];
  const float* b4 = (const float*)d_in[10];
  const int* idx1 = (const int*)d_in[11];
  const int* idx2 = (const int*)d_in[12];
  int ns = in_sizes[11];
  int n = 2 * ns;
  int npad = (n + 127) & ~127;
  int nt = npad / 128;
  int ntri = nt * (nt + 1) / 2;
  int nrowblk = (npad + 255) / 256;

  char* wp = (char*)d_ws;
  size_t off = 0;
  auto alloc = [&](size_t bytes) -> void* {
    void* p = wp + off;
    off += (bytes + 255) & ~(size_t)255;
    return p;
  };
  int*   i0  = (int*)alloc((size_t)S * 4);
  int*   i1  = (int*)alloc((size_t)S * 4);
  float* g0  = (float*)alloc((size_t)S * 4);
  float* g1  = (float*)alloc((size_t)S * 4);
  float* selpart = (float*)alloc((size_t)1024 * 16 * 4);
  float* ei  = (float*)alloc((size_t)E * 2 * M * 4);
  float* h1  = (float*)alloc((size_t)E * 2 * H1 * 4);
  float* h2  = (float*)alloc((size_t)E * 2 * H2 * 4);
  float* h3  = (float*)alloc((size_t)E * 2 * H3 * 4);
  float* eo  = (float*)alloc((size_t)E * 2 * CC * 4);
  float* G32 = (float*)alloc((size_t)1024 * 4);
  float* rowg = (float*)alloc((size_t)npad * 4);
  int*   rowe = (int*)alloc((size_t)npad * 4);
  float* wpart = (float*)alloc((size_t)nrowblk * 64 * 4);
  int*   cpart = (int*)alloc((size_t)nrowblk * 32 * 4);
  float* srowg = (float*)alloc((size_t)npad * 4);
  float* srowA = (float*)alloc((size_t)npad * 4);
  int*   srowe = (int*)alloc((size_t)npad * 4);
  float* srowsg = (float*)alloc((size_t)npad * 4);
  float* cl2 = (float*)alloc(16);
  double* bsum = (double*)alloc((size_t)ntri * 8);
  int* counters = (int*)alloc(256);
  (void)ws_size; (void)n_in; (void)out_size;

  float* out      = (float*)d_out;
  float* out_sel0 = out + (size_t)S * CC;
  float* out_bal  = out + (size_t)S * CC + (size_t)S * E * 2;
  float* out_dist = out_bal + 1;

  k_route<<<S / 4, 256, 0, stream>>>(x, noise, Wr, i0, i1, g0, g1, out_sel0, selpart, counters);
  k_gather<<<128, 1024, 0, stream>>>(x, i0, i1, g0, g1, ei);
  k_layer<M, H1, true><<<(E * H1 + 3) / 4, 256, 0, stream>>>(ei, W1, b1, h1);
  k_layer<H1, H2, true><<<(E * H2 + 3) / 4, 256, 0, stream>>>(h1, W2, b2, h2);
  k_layer<H2, H3, true><<<(E * H3 + 3) / 4, 256, 0, stream>>>(h2, W3, b3, h3);
  k_layer<H3, CC, false><<<(E * CC + 3) / 4, 256, 0, stream>>>(h3, W4, b4, eo);
  k_gprep<<<1 + nrowblk, 256, 0, stream>>>(eo, selpart, idx1, idx2, i0, i1, g0, g1,
                                           G32, rowg, rowe, wpart, cpart, out_bal, ns, n, npad);
  k_mid<<<nrowblk, 256, 0, stream>>>(G32, wpart, cpart, rowg, rowe,
                                     srowg, srowA, srowe, srowsg, cl2, ns, n, npad, nrowblk);
  k_tail<<<ntri + 2048, 256, 0, stream>>>(eo, i0, i1, g0, g1, out, srowg, srowA, srowe,
                                          srowsg, G32, cl2, bsum, out_dist, ns, n, nt, ntri,
                                          counters);
}

// Round 9
// 158.521 us; speedup vs baseline: 1.2074x; 1.2074x over previous
//
#include <hip/hip_runtime.h>

constexpr int S = 4096, M = 512, E = 16, CC = 128;
constexpr int H1 = 500, H2 = 500, H3 = 2000;
constexpr int TB = 256;   // mmd tile size

// fused: select = x@Wr^T + noise; top2; sel0 output; per-block column partials; zero counter
__global__ void k_route(const float* __restrict__ x, const float* __restrict__ noise,
                        const float* __restrict__ Wr, int* __restrict__ i0, int* __restrict__ i1,
                        float* __restrict__ g0, float* __restrict__ g1,
                        float* __restrict__ sel0, float* __restrict__ selpart,
                        int* __restrict__ counters) {
  if (blockIdx.x == 0 && threadIdx.x == 0) { counters[0] = 0; }
  int wid = threadIdx.x >> 6, lane = threadIdx.x & 63;
  int s = blockIdx.x * 4 + wid;
  const float* xr = x + (size_t)s * M;
  float xv[8];
#pragma unroll
  for (int c = 0; c < 8; ++c) xv[c] = xr[lane + 64 * c];
  float v[E];
#pragma unroll
  for (int e = 0; e < E; ++e) {
    const float* wr = Wr + (size_t)e * M;
    float acc = 0.f;
#pragma unroll
    for (int c = 0; c < 8; ++c) acc = fmaf(xv[c], wr[lane + 64 * c], acc);
#pragma unroll
    for (int off = 32; off; off >>= 1) acc += __shfl_xor(acc, off);
    v[e] = acc + noise[s * E + e];
  }
  int a0 = 0; float m0 = v[0];
#pragma unroll
  for (int e = 1; e < E; ++e) if (v[e] > m0) { m0 = v[e]; a0 = e; }
  int a1 = -1; float m1 = -3.4e38f;
#pragma unroll
  for (int e = 0; e < E; ++e) if (e != a0 && v[e] > m1) { m1 = v[e]; a1 = e; }
  __shared__ float vsh[4][16];
  if (lane < 16) vsh[wid][lane] = v[lane];
  if (lane == 0) { i0[s] = a0; i1[s] = a1; g0[s] = m0; g1[s] = m1; }
  if (lane < 16) {
    int e = lane;
    sel0[(size_t)s * 32 + e * 2 + 0] = (e == a0 && m0 != 0.f) ? 1.f : 0.f;
    sel0[(size_t)s * 32 + e * 2 + 1] = (e == a1 && m1 != 0.f) ? 1.f : 0.f;
  }
  __syncthreads();
  if (threadIdx.x < 16) {
    int e = threadIdx.x;
    selpart[blockIdx.x * 16 + e] = vsh[0][e] + vsh[1][e] + vsh[2][e] + vsh[3][e];
  }
}

// fused lists+gather+reduce: block=(ek,chunk); 8 groups of 128 threads scan 512-token segments
__global__ __launch_bounds__(1024) void k_gather(const float* __restrict__ x,
                        const int* __restrict__ i0, const int* __restrict__ i1,
                        const float* __restrict__ g0, const float* __restrict__ g1,
                        float* __restrict__ ei) {
  __shared__ int rsi[S];
  __shared__ float rsg[S];
  __shared__ float gacc[8][128];
  int b = blockIdx.x;                 // 128 = ek*4 + chunk
  int chunk = b & 3, ek = b >> 2;
  int k = ek & 1, e = ek >> 1;
  const int* route = k ? i1 : i0;
  const float* gg = k ? g1 : g0;
  int t = threadIdx.x;
  for (int i = t; i < S; i += 1024) { rsi[i] = route[i]; rsg[i] = gg[i]; }
  __syncthreads();
  int g = t >> 7, dl = t & 127;
  int d = chunk * 128 + dl;
  float acc = 0.f;
  int q0 = g * 512;
  for (int q = q0; q < q0 + 512; ++q) {
    if (rsi[q] == e && rsg[q] != 0.f) acc += x[(size_t)q * M + d];
  }
  gacc[g][dl] = acc;
  __syncthreads();
  if (t < 128) {
    float ssum = 0.f;
#pragma unroll
    for (int g2 = 0; g2 < 8; ++g2) ssum += gacc[g2][t];
    ei[ek * M + chunk * 128 + t] = ssum;
  }
}

// generic MLP layer: wave per (e,h) output neuron, both k rows at once
template <int DIN, int HOUT, bool RELU>
__global__ void k_layer(const float* __restrict__ in, const float* __restrict__ W,
                        const float* __restrict__ bias, float* __restrict__ out) {
  int w = (blockIdx.x * blockDim.x + threadIdx.x) >> 6;
  int lane = threadIdx.x & 63;
  if (w >= E * HOUT) return;
  int e = w / HOUT, h = w - e * HOUT;
  const float* wr = W + ((size_t)e * HOUT + h) * DIN;
  const float* in0 = in + (size_t)(e * 2 + 0) * DIN;
  const float* in1 = in + (size_t)(e * 2 + 1) * DIN;
  float a0 = 0.f, a1 = 0.f;
  for (int m = lane; m < DIN; m += 64) {
    float wv = wr[m];
    a0 += wv * in0[m];
    a1 += wv * in1[m];
  }
#pragma unroll
  for (int off = 32; off; off >>= 1) {
    a0 += __shfl_xor(a0, off);
    a1 += __shfl_xor(a1, off);
  }
  if (lane == 0) {
    float bb = bias[e * HOUT + h];
    float o0 = a0 + bb, o1 = a1 + bb;
    if (RELU) { o0 = fmaxf(o0, 0.f); o1 = fmaxf(o1, 0.f); }
    out[(size_t)(e * 2 + 0) * HOUT + h] = o0;
    out[(size_t)(e * 2 + 1) * HOUT + h] = o1;
  }
}

// gprep: block 0 = Gram32 + balance; blocks 1.. = row scalars + per-ek w/w2/count partials
__global__ __launch_bounds__(256) void k_gprep(const float* __restrict__ eo,
                        const float* __restrict__ selpart,
                        const int* __restrict__ idx1, const int* __restrict__ idx2,
                        const int* __restrict__ i0, const int* __restrict__ i1,
                        const float* __restrict__ g0, const float* __restrict__ g1,
                        float* __restrict__ G32, float* __restrict__ rowg,
                        int* __restrict__ rowe, float* __restrict__ wpart,
                        int* __restrict__ cpart,
                        float* __restrict__ outb, int ns, int ncnt, int npad) {
  int t = threadIdx.x;
  if (blockIdx.x == 0) {
    __shared__ float Es[32 * 132];
    __shared__ double red_d[256];
    __shared__ float dpl[16];
    for (int i = t; i < 32 * 128; i += 256) Es[(i >> 7) * 132 + (i & 127)] = eo[i];
    __syncthreads();
    for (int p = t; p < 1024; p += 256) {
      int u = p >> 5, v = p & 31;
      float s = 0.f;
#pragma unroll 8
      for (int d = 0; d < 128; ++d) s = fmaf(Es[u * 132 + d], Es[v * 132 + d], s);
      G32[p] = s;
    }
    // balance loss
    int e2 = t & 15, r0 = t >> 4;
    double acc = 0.0;
    for (int b2 = r0; b2 < 1024; b2 += 16) acc += (double)selpart[b2 * 16 + e2];
    red_d[t] = acc;
    __syncthreads();
    for (int off = 128; off >= 16; off >>= 1) { if (t < off) red_d[t] += red_d[t + off]; __syncthreads(); }
    if (t < 16) dpl[t] = (float)(red_d[t] / (double)S);
    __syncthreads();
    double acc2 = 0.0;
    for (int s2 = t; s2 < S; s2 += 256) acc2 += 0.5 * ((double)dpl[i0[s2]] + (double)dpl[i1[s2]]);
    red_d[t] = acc2;
    __syncthreads();
    for (int off = 128; off; off >>= 1) { if (t < off) red_d[t] += red_d[t + off]; __syncthreads(); }
    if (t == 0) outb[0] = (float)(red_d[0] / 256.0);
    return;
  }
  // rows blocks: 1 row per thread
  int blk = blockIdx.x - 1;
  int r = blk * 256 + t;
  float g = 0.f; int ek = 0;
  bool valid = (r < npad);
  if (r < ns)        { int tk = idx1[r];      ek = i0[tk] * 2 + 0; g = g0[tk]; }
  else if (r < ncnt) { int tk = idx2[r - ns]; ek = i1[tk] * 2 + 1; g = g1[tk]; }
  if (valid) { rowg[r] = g; rowe[r] = ek; }
  int ekb = valid ? ek : -1;
  __shared__ float sw[4][32], sw2[4][32];
  __shared__ int sc[4][32];
  int lane = t & 63, w = t >> 6;
  float g2 = g * g;
  for (int e = 0; e < 32; ++e) {
    unsigned long long m = __ballot(ekb == e);
    float vw = (ekb == e) ? g : 0.f;
    float vw2 = (ekb == e) ? g2 : 0.f;
#pragma unroll
    for (int off = 32; off; off >>= 1) { vw += __shfl_xor(vw, off); vw2 += __shfl_xor(vw2, off); }
    if (lane == 0) { sw[w][e] = vw; sw2[w][e] = vw2; sc[w][e] = __popcll(m); }
  }
  __syncthreads();
  if (t < 32) {
    wpart[blk * 64 + t]      = sw[0][t] + sw[1][t] + sw[2][t] + sw[3][t];
    wpart[blk * 64 + 32 + t] = sw2[0][t] + sw2[1][t] + sw2[2][t] + sw2[3][t];
    cpart[blk * 32 + t]      = sc[0][t] + sc[1][t] + sc[2][t] + sc[3][t];
  }
}

// mid: per-block expert-sort of 256 rows (deterministic counting sort, fully parallel scans) + cl
__global__ __launch_bounds__(256) void k_mid(const float* __restrict__ G32,
                        const float* __restrict__ wpart, const int* __restrict__ cpart,
                        const float* __restrict__ rowg, const int* __restrict__ rowe,
                        float* __restrict__ srowg, float* __restrict__ srowA,
                        int* __restrict__ srowe, float* __restrict__ srowsg,
                        float* __restrict__ cl2,
                        int ns, int ncnt, int npad, int nrowblk) {
  __shared__ int cpl[32 * 32];        // up to 32 row-blocks
  __shared__ int total_s[32];
  __shared__ int offmy[32];
  __shared__ float wf[32], w2f[32];
  __shared__ double redd[256];
  __shared__ int wcnt[4][32];
  __shared__ float c_sh;
  int t = threadIdx.x, blk = blockIdx.x;
  for (int i = t; i < nrowblk * 32; i += 256) cpl[i] = cpart[i];
  if (t < 32) {
    float sw = 0.f, sw2 = 0.f;
    for (int b = 0; b < nrowblk; ++b) { sw += wpart[b * 64 + t]; sw2 += wpart[b * 64 + 32 + t]; }
    wf[t] = sw; w2f[t] = sw2;
  }
  __syncthreads();
  if (t < 32) {
    int tot = 0;
    for (int b = 0; b < nrowblk; ++b) tot += cpl[b * 32 + t];
    total_s[t] = tot;
  }
  __syncthreads();
  if (t < 32) {
    int off = 0;
    for (int e = 0; e < t; ++e) off += total_s[e];      // parallel across 32 threads
    for (int b = 0; b < blk; ++b) off += cpl[b * 32 + t];
    offmy[t] = off;
  }
  // c = 1/(bw*16)  (identical in every block; block 0 publishes for k_tail)
  double part = 0.0;
  for (int i = t; i < 1024; i += 256)
    part += (double)wf[i >> 5] * (double)wf[i & 31] * (double)G32[i];
  redd[t] = part;
  __syncthreads();
  for (int off = 128; off; off >>= 1) { if (t < off) redd[t] += redd[t + off]; __syncthreads(); }
  double wGw = redd[0];
  __syncthreads();
  redd[t] = (t < 32) ? (double)w2f[t] * (double)G32[t * 33] : 0.0;
  __syncthreads();
  for (int off = 128; off; off >>= 1) { if (t < off) redd[t] += redd[t + off]; __syncthreads(); }
  if (t == 0) {
    double nn = (double)ncnt;
    double sumd2 = 2.0 * nn * redd[0] - 2.0 * wGw;
    double bw = sumd2 / (nn * nn - nn) / 4.0;
    c_sh = (float)(1.0 / (bw * 16.0));
    if (blk == 0) cl2[0] = c_sh;
  }
  __syncthreads();
  float c = c_sh;
  // stable permutation of my 256 rows (lane order within wave, wave order)
  int r = blk * 256 + t;
  bool valid = (r < npad);
  float g = valid ? rowg[r] : 0.f;
  int ek = valid ? rowe[r] : -1;
  float sg = (r < ns) ? 1.f : (r < ncnt ? -1.f : 0.f);
  int lane = t & 63, w = t >> 6;
  int myrank = 0;
  for (int e = 0; e < 32; ++e) {
    unsigned long long m = __ballot(ek == e);
    if (ek == e) myrank = __popcll(m & ((1ull << lane) - 1ull));
    if (lane == 0) wcnt[w][e] = __popcll(m);
  }
  __syncthreads();
  if (valid) {
    int woff = 0;
    for (int w2 = 0; w2 < w; ++w2) woff += wcnt[w2][ek];
    int dest = offmy[ek] + woff + myrank;
    srowg[dest] = g;
    srowsg[dest] = sg;
    srowe[dest] = ek;
    srowA[dest] = c * g * g * G32[ek * 33];
  }
}

// tail: blocks [0,ntri) = 256x256 mmd tiles on sorted rows; blocks [ntri,+1024) = token output;
//       last mmd block = final reduce. 512 threads.
__global__ __launch_bounds__(512) void k_tail(const float* __restrict__ eo,
                      const int* __restrict__ i0, const int* __restrict__ i1,
                      const float* __restrict__ g0, const float* __restrict__ g1,
                      float* __restrict__ out,
                      const float* __restrict__ srowg, const float* __restrict__ srowA,
                      const int* __restrict__ srowe, const float* __restrict__ srowsg,
                      const float* __restrict__ G32, const float* __restrict__ cl2,
                      double* __restrict__ bsum, float* __restrict__ out_dist,
                      int ns, int ncnt, int nt, int ntri, int* __restrict__ counters) {
  int b = blockIdx.x, tid = threadIdx.x;
  if (b >= ntri) {
    int idx = (b - ntri) * 512 + tid;
    int s = idx >> 7, d = idx & (CC - 1);
    out[idx] = g0[s] * eo[(i0[s] * 2 + 0) * CC + d] + g1[s] * eo[(i1[s] * 2 + 1) * CC + d];
    return;
  }
  __shared__ float K2[1056];
  __shared__ float gAs[264], aAs[264], sAs[264];
  __shared__ int   eAs[264];
  __shared__ float gBs[264], aBs[264], sBs[264];
  __shared__ int   eBs[264];
  __shared__ float wred[8];
  __shared__ double redd[512];
  __shared__ int lastflag;

  int L = b;
  int bi = 0, rem = L;
  while (rem >= nt - bi) { rem -= nt - bi; ++bi; }
  int bj = bi + rem;
  const int ib = bi * TB, jb = bj * TB;

  float c = cl2[0];
  for (int i = tid; i < 1024; i += 512) K2[(i >> 5) * 33 + (i & 31)] = 2.f * c * G32[i];
  // stage row scalars: row r stored at p = (r&7)*33 + (r>>3)
  if (tid < TB) {
    int r = tid, p = (r & 7) * 33 + (r >> 3);
    gAs[p] = srowg[ib + r]; aAs[p] = srowA[ib + r];
    eAs[p] = srowe[ib + r] * 33; sAs[p] = srowsg[ib + r];
  } else {
    int r = tid - TB, p = (r & 7) * 33 + (r >> 3);
    gBs[p] = srowg[jb + r]; aBs[p] = srowA[jb + r];
    eBs[p] = srowe[jb + r]; sBs[p] = srowsg[jb + r];
  }
  __syncthreads();

  int ti = tid & 15, tjj = tid >> 4;       // 16 row-groups x 32 col-groups
  float gj[8], Aj[8], sgj[8]; int ej[8];
#pragma unroll
  for (int q = 0; q < 8; ++q) {            // cols j = tjj*8+q -> p = q*33 + tjj
    int p = q * 33 + tjj;
    gj[q] = gBs[p]; Aj[q] = aBs[p]; ej[q] = eBs[p]; sgj[q] = sBs[p];
  }
  float tsum = 0.f;
#pragma unroll
  for (int rb = 0; rb < 2; ++rb) {
    float gi[8], Ai[8], sgi[8]; int ei[8];
#pragma unroll
    for (int r = 0; r < 8; ++r) {          // rows i = ti*16 + rb*8 + r -> p = r*33 + ti*2+rb
      int p = r * 33 + ti * 2 + rb;
      gi[r] = gAs[p]; Ai[r] = aAs[p]; ei[r] = eAs[p]; sgi[r] = sAs[p];
    }
#pragma unroll
    for (int r = 0; r < 8; ++r) {
#pragma unroll
      for (int q = 0; q < 8; ++q) {
        float gg = gi[r] * gj[q];
        float arg = fmaf(K2[ei[r] + ej[q]], gg, -(Ai[r] + Aj[q]));
        float t = __expf(arg);
        float t2 = t * t;   float s5 = t + t2;
        float t4 = t2 * t2; s5 += t4;
        float t8 = t4 * t4; s5 += t8;
        float t16 = t8 * t8; s5 += t16;
        tsum = fmaf(sgi[r] * sgj[q], s5, tsum);
      }
    }
  }
#pragma unroll
  for (int off = 32; off; off >>= 1) tsum += __shfl_xor(tsum, off);
  if ((tid & 63) == 0) wred[tid >> 6] = tsum;
  __syncthreads();
  if (tid == 0) {
    float sblk = 0.f;
#pragma unroll
    for (int w = 0; w < 8; ++w) sblk += wred[w];
    bsum[L] = (double)sblk * ((bi == bj) ? 1.0 : 2.0);
  }

  // last-mmd-block election -> final reduce (fixed order, deterministic)
  if (tid == 0) {
    __threadfence();
    int old = atomicAdd(&counters[0], 1);
    lastflag = (old == ntri - 1) ? 1 : 0;
  }
  __syncthreads();
  if (!lastflag) return;
  __threadfence();
  double acc = 0.0;
  for (int i = tid; i < ntri; i += 512) acc += bsum[i];
  redd[tid] = acc;
  __syncthreads();
  for (int off = 256; off; off >>= 1) { if (tid < off) redd[tid] += redd[tid + off]; __syncthreads(); }
  if (tid == 0) out_dist[0] = (float)(-redd[0] / ((double)ns * (double)ns));
}

extern "C" void kernel_launch(void* const* d_in, const int* in_sizes, int n_in,
                              void* d_out, int out_size, void* d_ws, size_t ws_size,
                              hipStream_t stream) {
  const float* x  = (const float*)d_in[0];
  const float* noise = (const float*)d_in[1];
  const float* Wr = (const float*)d_in[2];
  const float* W1 = (const float*)d_in[3];
  const float* b1 = (const float*)d_in[4];
  const float* W2 = (const float*)d_in[5];
  const float* b2 = (const float*)d_in[6];
  const float* W3 = (const float*)d_in[7];
  const float* b3 = (const float*)d_in[8];
  const float* W4 = (const float*)d_in[9];
  const float* b4 = (const float*)d_in[10];
  const int* idx1 = (const int*)d_in[11];
  const int* idx2 = (const int*)d_in[12];
  int ns = in_sizes[11];
  int n = 2 * ns;
  int npad = (n + 255) & ~255;
  int nt = npad / TB;
  int ntri = nt * (nt + 1) / 2;
  int nrowblk = npad / 256;

  char* wp = (char*)d_ws;
  size_t off = 0;
  auto alloc = [&](size_t bytes) -> void* {
    void* p = wp + off;
    off += (bytes + 255) & ~(size_t)255;
    return p;
  };
  int*   i0  = (int*)alloc((size_t)S * 4);
  int*   i1  = (int*)alloc((size_t)S * 4);
  float* g0  = (float*)alloc((size_t)S * 4);
  float* g1  = (float*)alloc((size_t)S * 4);
  float* selpart = (float*)alloc((size_t)1024 * 16 * 4);
  float* ei  = (float*)alloc((size_t)E * 2 * M * 4);
  float* h1  = (float*)alloc((size_t)E * 2 * H1 * 4);
  float* h2  = (float*)alloc((size_t)E * 2 * H2 * 4);
  float* h3  = (float*)alloc((size_t)E * 2 * H3 * 4);
  float* eo  = (float*)alloc((size_t)E * 2 * CC * 4);
  float* G32 = (float*)alloc((size_t)1024 * 4);
  float* rowg = (float*)alloc((size_t)npad * 4);
  int*   rowe = (int*)alloc((size_t)npad * 4);
  float* wpart = (float*)alloc((size_t)nrowblk * 64 * 4);
  int*   cpart = (int*)alloc((size_t)nrowblk * 32 * 4);
  float* srowg = (float*)alloc((size_t)npad * 4);
  float* srowA = (float*)alloc((size_t)npad * 4);
  int*   srowe = (int*)alloc((size_t)npad * 4);
  float* srowsg = (float*)alloc((size_t)npad * 4);
  float* cl2 = (float*)alloc(16);
  double* bsum = (double*)alloc((size_t)ntri * 8);
  int* counters = (int*)alloc(256);
  (void)ws_size; (void)n_in; (void)out_size;

  float* out      = (float*)d_out;
  float* out_sel0 = out + (size_t)S * CC;
  float* out_bal  = out + (size_t)S * CC + (size_t)S * E * 2;
  float* out_dist = out_bal + 1;

  k_route<<<S / 4, 256, 0, stream>>>(x, noise, Wr, i0, i1, g0, g1, out_sel0, selpart, counters);
  k_gather<<<128, 1024, 0, stream>>>(x, i0, i1, g0, g1, ei);
  k_layer<M, H1, true><<<(E * H1 + 3) / 4, 256, 0, stream>>>(ei, W1, b1, h1);
  k_layer<H1, H2, true><<<(E * H2 + 3) / 4, 256, 0, stream>>>(h1, W2, b2, h2);
  k_layer<H2, H3, true><<<(E * H3 + 3) / 4, 256, 0, stream>>>(h2, W3, b3, h3);
  k_layer<H3, CC, false><<<(E * CC + 3) / 4, 256, 0, stream>>>(h3, W4, b4, eo);
  k_gprep<<<1 + nrowblk, 256, 0, stream>>>(eo, selpart, idx1, idx2, i0, i1, g0, g1,
                                           G32, rowg, rowe, wpart, cpart, out_bal, ns, n, npad);
  k_mid<<<nrowblk, 256, 0, stream>>>(G32, wpart, cpart, rowg, rowe,
                                     srowg, srowA, srowe, srowsg, cl2, ns, n, npad, nrowblk);
  k_tail<<<ntri + (S * CC) / 512, 512, 0, stream>>>(eo, i0, i1, g0, g1, out, srowg, srowA,
                                                    srowe, srowsg, G32, cl2, bsum, out_dist,
                                                    ns, n, nt, ntri, counters);
}

// Round 10
// 155.042 us; speedup vs baseline: 1.2345x; 1.0224x over previous
//
#include <hip/hip_runtime.h>

constexpr int S = 4096, M = 512, E = 16, CC = 128;
constexpr int H1 = 500, H2 = 500, H3 = 2000;
constexpr int TB = 256;   // mmd tile size

// fused: select = x@Wr^T + noise; top2; sel0 output; per-block column partials; zero counter
__global__ void k_route(const float* __restrict__ x, const float* __restrict__ noise,
                        const float* __restrict__ Wr, int* __restrict__ i0, int* __restrict__ i1,
                        float* __restrict__ g0, float* __restrict__ g1,
                        float* __restrict__ sel0, float* __restrict__ selpart,
                        int* __restrict__ counters) {
  if (blockIdx.x == 0 && threadIdx.x == 0) { counters[0] = 0; }
  int wid = threadIdx.x >> 6, lane = threadIdx.x & 63;
  int s = blockIdx.x * 4 + wid;
  const float* xr = x + (size_t)s * M;
  float xv[8];
#pragma unroll
  for (int c = 0; c < 8; ++c) xv[c] = xr[lane + 64 * c];
  float v[E];
#pragma unroll
  for (int e = 0; e < E; ++e) {
    const float* wr = Wr + (size_t)e * M;
    float acc = 0.f;
#pragma unroll
    for (int c = 0; c < 8; ++c) acc = fmaf(xv[c], wr[lane + 64 * c], acc);
#pragma unroll
    for (int off = 32; off; off >>= 1) acc += __shfl_xor(acc, off);
    v[e] = acc + noise[s * E + e];
  }
  int a0 = 0; float m0 = v[0];
#pragma unroll
  for (int e = 1; e < E; ++e) if (v[e] > m0) { m0 = v[e]; a0 = e; }
  int a1 = -1; float m1 = -3.4e38f;
#pragma unroll
  for (int e = 0; e < E; ++e) if (e != a0 && v[e] > m1) { m1 = v[e]; a1 = e; }
  __shared__ float vsh[4][16];
  if (lane < 16) vsh[wid][lane] = v[lane];
  if (lane == 0) { i0[s] = a0; i1[s] = a1; g0[s] = m0; g1[s] = m1; }
  if (lane < 16) {
    int e = lane;
    sel0[(size_t)s * 32 + e * 2 + 0] = (e == a0 && m0 != 0.f) ? 1.f : 0.f;
    sel0[(size_t)s * 32 + e * 2 + 1] = (e == a1 && m1 != 0.f) ? 1.f : 0.f;
  }
  __syncthreads();
  if (threadIdx.x < 16) {
    int e = threadIdx.x;
    selpart[blockIdx.x * 16 + e] = vsh[0][e] + vsh[1][e] + vsh[2][e] + vsh[3][e];
  }
}

// segmented gather partials: block = (ek*4 + chunk)*8 + seg; 128 threads scan 512 tokens
__global__ __launch_bounds__(128) void k_gpart(const float* __restrict__ x,
                        const int* __restrict__ i0, const int* __restrict__ i1,
                        const float* __restrict__ g0, const float* __restrict__ g1,
                        float* __restrict__ gpart) {
  __shared__ int rsi[512];
  __shared__ float rsg[512];
  int b = blockIdx.x;                  // 1024
  int seg = b & 7, chunk = (b >> 3) & 3, ek = b >> 5;
  int k = ek & 1, e = ek >> 1;
  const int* route = k ? i1 : i0;
  const float* gg = k ? g1 : g0;
  int t = threadIdx.x;                 // 128
  int s0 = seg * 512;
#pragma unroll
  for (int i = 0; i < 4; ++i) {
    rsi[t + i * 128] = route[s0 + t + i * 128];
    rsg[t + i * 128] = gg[s0 + t + i * 128];
  }
  __syncthreads();
  int d = chunk * 128 + t;
  float acc = 0.f;
  for (int q = 0; q < 512; ++q) {
    if (rsi[q] == e && rsg[q] != 0.f) acc += x[(size_t)(s0 + q) * M + d];
  }
  gpart[(size_t)seg * (32 * M) + ek * M + d] = acc;
}

// fixed-order 8-way reduce of gather partials
__global__ void k_gred(const float* __restrict__ gpart, float* __restrict__ ei) {
  int idx = blockIdx.x * blockDim.x + threadIdx.x;   // 16384
  float acc = 0.f;
#pragma unroll
  for (int sg = 0; sg < 8; ++sg) acc += gpart[(size_t)sg * (32 * M) + idx];
  ei[idx] = acc;
}

// generic MLP layer: wave per (e,h) output neuron, both k rows at once
template <int DIN, int HOUT, bool RELU>
__global__ void k_layer(const float* __restrict__ in, const float* __restrict__ W,
                        const float* __restrict__ bias, float* __restrict__ out) {
  int w = (blockIdx.x * blockDim.x + threadIdx.x) >> 6;
  int lane = threadIdx.x & 63;
  if (w >= E * HOUT) return;
  int e = w / HOUT, h = w - e * HOUT;
  const float* wr = W + ((size_t)e * HOUT + h) * DIN;
  const float* in0 = in + (size_t)(e * 2 + 0) * DIN;
  const float* in1 = in + (size_t)(e * 2 + 1) * DIN;
  float a0 = 0.f, a1 = 0.f;
  for (int m = lane; m < DIN; m += 64) {
    float wv = wr[m];
    a0 += wv * in0[m];
    a1 += wv * in1[m];
  }
#pragma unroll
  for (int off = 32; off; off >>= 1) {
    a0 += __shfl_xor(a0, off);
    a1 += __shfl_xor(a1, off);
  }
  if (lane == 0) {
    float bb = bias[e * HOUT + h];
    float o0 = a0 + bb, o1 = a1 + bb;
    if (RELU) { o0 = fmaxf(o0, 0.f); o1 = fmaxf(o1, 0.f); }
    out[(size_t)(e * 2 + 0) * HOUT + h] = o0;
    out[(size_t)(e * 2 + 1) * HOUT + h] = o1;
  }
}

// gprep: block 0 = Gram32 + balance; blocks 1.. = row scalars + per-ek w/w2/count partials
__global__ __launch_bounds__(256) void k_gprep(const float* __restrict__ eo,
                        const float* __restrict__ selpart,
                        const int* __restrict__ idx1, const int* __restrict__ idx2,
                        const int* __restrict__ i0, const int* __restrict__ i1,
                        const float* __restrict__ g0, const float* __restrict__ g1,
                        float* __restrict__ G32, float* __restrict__ rowg,
                        int* __restrict__ rowe, float* __restrict__ wpart,
                        int* __restrict__ cpart,
                        float* __restrict__ outb, int ns, int ncnt, int npad) {
  int t = threadIdx.x;
  if (blockIdx.x == 0) {
    __shared__ float Es[32 * 132];
    __shared__ double red_d[256];
    __shared__ float dpl[16];
    for (int i = t; i < 32 * 128; i += 256) Es[(i >> 7) * 132 + (i & 127)] = eo[i];
    __syncthreads();
    for (int p = t; p < 1024; p += 256) {
      int u = p >> 5, v = p & 31;
      float s = 0.f;
#pragma unroll 8
      for (int d = 0; d < 128; ++d) s = fmaf(Es[u * 132 + d], Es[v * 132 + d], s);
      G32[p] = s;
    }
    // balance loss
    int e2 = t & 15, r0 = t >> 4;
    double acc = 0.0;
    for (int b2 = r0; b2 < 1024; b2 += 16) acc += (double)selpart[b2 * 16 + e2];
    red_d[t] = acc;
    __syncthreads();
    for (int off = 128; off >= 16; off >>= 1) { if (t < off) red_d[t] += red_d[t + off]; __syncthreads(); }
    if (t < 16) dpl[t] = (float)(red_d[t] / (double)S);
    __syncthreads();
    double acc2 = 0.0;
    for (int s2 = t; s2 < S; s2 += 256) acc2 += 0.5 * ((double)dpl[i0[s2]] + (double)dpl[i1[s2]]);
    red_d[t] = acc2;
    __syncthreads();
    for (int off = 128; off; off >>= 1) { if (t < off) red_d[t] += red_d[t + off]; __syncthreads(); }
    if (t == 0) outb[0] = (float)(red_d[0] / 256.0);
    return;
  }
  // rows blocks: 1 row per thread
  int blk = blockIdx.x - 1;
  int r = blk * 256 + t;
  float g = 0.f; int ek = 0;
  bool valid = (r < npad);
  if (r < ns)        { int tk = idx1[r];      ek = i0[tk] * 2 + 0; g = g0[tk]; }
  else if (r < ncnt) { int tk = idx2[r - ns]; ek = i1[tk] * 2 + 1; g = g1[tk]; }
  if (valid) { rowg[r] = g; rowe[r] = ek; }
  int ekb = valid ? ek : -1;
  __shared__ float sw[4][32], sw2[4][32];
  __shared__ int sc[4][32];
  int lane = t & 63, w = t >> 6;
  float g2 = g * g;
  for (int e = 0; e < 32; ++e) {
    unsigned long long m = __ballot(ekb == e);
    float vw = (ekb == e) ? g : 0.f;
    float vw2 = (ekb == e) ? g2 : 0.f;
#pragma unroll
    for (int off = 32; off; off >>= 1) { vw += __shfl_xor(vw, off); vw2 += __shfl_xor(vw2, off); }
    if (lane == 0) { sw[w][e] = vw; sw2[w][e] = vw2; sc[w][e] = __popcll(m); }
  }
  __syncthreads();
  if (t < 32) {
    wpart[blk * 64 + t]      = sw[0][t] + sw[1][t] + sw[2][t] + sw[3][t];
    wpart[blk * 64 + 32 + t] = sw2[0][t] + sw2[1][t] + sw2[2][t] + sw2[3][t];
    cpart[blk * 32 + t]      = sc[0][t] + sc[1][t] + sc[2][t] + sc[3][t];
  }
}

// mid: per-block expert-sort of 256 rows (deterministic counting sort, fully parallel scans) + cl
__global__ __launch_bounds__(256) void k_mid(const float* __restrict__ G32,
                        const float* __restrict__ wpart, const int* __restrict__ cpart,
                        const float* __restrict__ rowg, const int* __restrict__ rowe,
                        float* __restrict__ srowg, float* __restrict__ srowA,
                        int* __restrict__ srowe, float* __restrict__ srowsg,
                        float* __restrict__ cl2,
                        int ns, int ncnt, int npad, int nrowblk) {
  __shared__ int cpl[32 * 32];        // up to 32 row-blocks
  __shared__ int total_s[32];
  __shared__ int offmy[32];
  __shared__ float wf[32], w2f[32];
  __shared__ double redd[256];
  __shared__ int wcnt[4][32];
  __shared__ float c_sh;
  int t = threadIdx.x, blk = blockIdx.x;
  for (int i = t; i < nrowblk * 32; i += 256) cpl[i] = cpart[i];
  if (t < 32) {
    float sw = 0.f, sw2 = 0.f;
    for (int b = 0; b < nrowblk; ++b) { sw += wpart[b * 64 + t]; sw2 += wpart[b * 64 + 32 + t]; }
    wf[t] = sw; w2f[t] = sw2;
  }
  __syncthreads();
  if (t < 32) {
    int tot = 0;
    for (int b = 0; b < nrowblk; ++b) tot += cpl[b * 32 + t];
    total_s[t] = tot;
  }
  __syncthreads();
  if (t < 32) {
    int off = 0;
    for (int e = 0; e < t; ++e) off += total_s[e];
    for (int b = 0; b < blk; ++b) off += cpl[b * 32 + t];
    offmy[t] = off;
  }
  // c = 1/(bw*16)  (identical in every block; block 0 publishes for k_tail)
  double part = 0.0;
  for (int i = t; i < 1024; i += 256)
    part += (double)wf[i >> 5] * (double)wf[i & 31] * (double)G32[i];
  redd[t] = part;
  __syncthreads();
  for (int off = 128; off; off >>= 1) { if (t < off) redd[t] += redd[t + off]; __syncthreads(); }
  double wGw = redd[0];
  __syncthreads();
  redd[t] = (t < 32) ? (double)w2f[t] * (double)G32[t * 33] : 0.0;
  __syncthreads();
  for (int off = 128; off; off >>= 1) { if (t < off) redd[t] += redd[t + off]; __syncthreads(); }
  if (t == 0) {
    double nn = (double)ncnt;
    double sumd2 = 2.0 * nn * redd[0] - 2.0 * wGw;
    double bw = sumd2 / (nn * nn - nn) / 4.0;
    c_sh = (float)(1.0 / (bw * 16.0));
    if (blk == 0) cl2[0] = c_sh;
  }
  __syncthreads();
  float c = c_sh;
  // stable permutation of my 256 rows (lane order within wave, wave order)
  int r = blk * 256 + t;
  bool valid = (r < npad);
  float g = valid ? rowg[r] : 0.f;
  int ek = valid ? rowe[r] : -1;
  float sg = (r < ns) ? 1.f : (r < ncnt ? -1.f : 0.f);
  int lane = t & 63, w = t >> 6;
  int myrank = 0;
  for (int e = 0; e < 32; ++e) {
    unsigned long long m = __ballot(ek == e);
    if (ek == e) myrank = __popcll(m & ((1ull << lane) - 1ull));
    if (lane == 0) wcnt[w][e] = __popcll(m);
  }
  __syncthreads();
  if (valid) {
    int woff = 0;
    for (int w2 = 0; w2 < w; ++w2) woff += wcnt[w2][ek];
    int dest = offmy[ek] + woff + myrank;
    srowg[dest] = g;
    srowsg[dest] = sg;
    srowe[dest] = ek;
    srowA[dest] = c * g * g * G32[ek * 33];
  }
}

// tail: blocks [0,ntri) = 256x256 mmd tiles on sorted rows; blocks [ntri,+1024) = token output;
//       last mmd block = final reduce. 512 threads.
__global__ __launch_bounds__(512) void k_tail(const float* __restrict__ eo,
                      const int* __restrict__ i0, const int* __restrict__ i1,
                      const float* __restrict__ g0, const float* __restrict__ g1,
                      float* __restrict__ out,
                      const float* __restrict__ srowg, const float* __restrict__ srowA,
                      const int* __restrict__ srowe, const float* __restrict__ srowsg,
                      const float* __restrict__ G32, const float* __restrict__ cl2,
                      double* __restrict__ bsum, float* __restrict__ out_dist,
                      int ns, int ncnt, int nt, int ntri, int* __restrict__ counters) {
  int b = blockIdx.x, tid = threadIdx.x;
  if (b >= ntri) {
    int idx = (b - ntri) * 512 + tid;
    int s = idx >> 7, d = idx & (CC - 1);
    out[idx] = g0[s] * eo[(i0[s] * 2 + 0) * CC + d] + g1[s] * eo[(i1[s] * 2 + 1) * CC + d];
    return;
  }
  __shared__ float K2[1056];
  __shared__ float gAs[264], aAs[264], sAs[264];
  __shared__ int   eAs[264];
  __shared__ float gBs[264], aBs[264], sBs[264];
  __shared__ int   eBs[264];
  __shared__ float wred[8];
  __shared__ double redd[512];
  __shared__ int lastflag;

  int L = b;
  int bi = 0, rem = L;
  while (rem >= nt - bi) { rem -= nt - bi; ++bi; }
  int bj = bi + rem;
  const int ib = bi * TB, jb = bj * TB;

  float c = cl2[0];
  for (int i = tid; i < 1024; i += 512) K2[(i >> 5) * 33 + (i & 31)] = 2.f * c * G32[i];
  // stage row scalars: row r stored at p = (r&7)*33 + (r>>3)
  if (tid < TB) {
    int r = tid, p = (r & 7) * 33 + (r >> 3);
    gAs[p] = srowg[ib + r]; aAs[p] = srowA[ib + r];
    eAs[p] = srowe[ib + r] * 33; sAs[p] = srowsg[ib + r];
  } else {
    int r = tid - TB, p = (r & 7) * 33 + (r >> 3);
    gBs[p] = srowg[jb + r]; aBs[p] = srowA[jb + r];
    eBs[p] = srowe[jb + r]; sBs[p] = srowsg[jb + r];
  }
  __syncthreads();

  int ti = tid & 15, tjj = tid >> 4;       // 16 row-groups x 32 col-groups
  float gj[8], Aj[8], sgj[8]; int ej[8];
#pragma unroll
  for (int q = 0; q < 8; ++q) {            // cols j = tjj*8+q -> p = q*33 + tjj
    int p = q * 33 + tjj;
    gj[q] = gBs[p]; Aj[q] = aBs[p]; ej[q] = eBs[p]; sgj[q] = sBs[p];
  }
  float tsum = 0.f;
#pragma unroll
  for (int rb = 0; rb < 2; ++rb) {
    float gi[8], Ai[8], sgi[8]; int ei[8];
#pragma unroll
    for (int r = 0; r < 8; ++r) {          // rows i = ti*16 + rb*8 + r -> p = r*33 + ti*2+rb
      int p = r * 33 + ti * 2 + rb;
      gi[r] = gAs[p]; Ai[r] = aAs[p]; ei[r] = eAs[p]; sgi[r] = sAs[p];
    }
#pragma unroll
    for (int r = 0; r < 8; ++r) {
#pragma unroll
      for (int q = 0; q < 8; ++q) {
        float gg = gi[r] * gj[q];
        float arg = fmaf(K2[ei[r] + ej[q]], gg, -(Ai[r] + Aj[q]));
        float t = __expf(arg);
        float t2 = t * t;   float s5 = t + t2;
        float t4 = t2 * t2; s5 += t4;
        float t8 = t4 * t4; s5 += t8;
        float t16 = t8 * t8; s5 += t16;
        tsum = fmaf(sgi[r] * sgj[q], s5, tsum);
      }
    }
  }
#pragma unroll
  for (int off = 32; off; off >>= 1) tsum += __shfl_xor(tsum, off);
  if ((tid & 63) == 0) wred[tid >> 6] = tsum;
  __syncthreads();
  if (tid == 0) {
    float sblk = 0.f;
#pragma unroll
    for (int w = 0; w < 8; ++w) sblk += wred[w];
    bsum[L] = (double)sblk * ((bi == bj) ? 1.0 : 2.0);
  }

  // last-mmd-block election -> final reduce (fixed order, deterministic)
  if (tid == 0) {
    __threadfence();
    int old = atomicAdd(&counters[0], 1);
    lastflag = (old == ntri - 1) ? 1 : 0;
  }
  __syncthreads();
  if (!lastflag) return;
  __threadfence();
  double acc = 0.0;
  for (int i = tid; i < ntri; i += 512) acc += bsum[i];
  redd[tid] = acc;
  __syncthreads();
  for (int off = 256; off; off >>= 1) { if (tid < off) redd[tid] += redd[tid + off]; __syncthreads(); }
  if (tid == 0) out_dist[0] = (float)(-redd[0] / ((double)ns * (double)ns));
}

extern "C" void kernel_launch(void* const* d_in, const int* in_sizes, int n_in,
                              void* d_out, int out_size, void* d_ws, size_t ws_size,
                              hipStream_t stream) {
  const float* x  = (const float*)d_in[0];
  const float* noise = (const float*)d_in[1];
  const float* Wr = (const float*)d_in[2];
  const float* W1 = (const float*)d_in[3];
  const float* b1 = (const float*)d_in[4];
  const float* W2 = (const float*)d_in[5];
  const float* b2 = (const float*)d_in[6];
  const float* W3 = (const float*)d_in[7];
  const float* b3 = (const float*)d_in[8];
  const float* W4 = (const float*)d_in[9];
  const float* b4 = (const float*)d_in[10];
  const int* idx1 = (const int*)d_in[11];
  const int* idx2 = (const int*)d_in[12];
  int ns = in_sizes[11];
  int n = 2 * ns;
  int npad = (n + 255) & ~255;
  int nt = npad / TB;
  int ntri = nt * (nt + 1) / 2;
  int nrowblk = npad / 256;

  char* wp = (char*)d_ws;
  size_t off = 0;
  auto alloc = [&](size_t bytes) -> void* {
    void* p = wp + off;
    off += (bytes + 255) & ~(size_t)255;
    return p;
  };
  int*   i0  = (int*)alloc((size_t)S * 4);
  int*   i1  = (int*)alloc((size_t)S * 4);
  float* g0  = (float*)alloc((size_t)S * 4);
  float* g1  = (float*)alloc((size_t)S * 4);
  float* selpart = (float*)alloc((size_t)1024 * 16 * 4);
  float* gpart = (float*)alloc((size_t)8 * 32 * M * 4);
  float* ei  = (float*)alloc((size_t)E * 2 * M * 4);
  float* h1  = (float*)alloc((size_t)E * 2 * H1 * 4);
  float* h2  = (float*)alloc((size_t)E * 2 * H2 * 4);
  float* h3  = (float*)alloc((size_t)E * 2 * H3 * 4);
  float* eo  = (float*)alloc((size_t)E * 2 * CC * 4);
  float* G32 = (float*)alloc((size_t)1024 * 4);
  float* rowg = (float*)alloc((size_t)npad * 4);
  int*   rowe = (int*)alloc((size_t)npad * 4);
  float* wpart = (float*)alloc((size_t)nrowblk * 64 * 4);
  int*   cpart = (int*)alloc((size_t)nrowblk * 32 * 4);
  float* srowg = (float*)alloc((size_t)npad * 4);
  float* srowA = (float*)alloc((size_t)npad * 4);
  int*   srowe = (int*)alloc((size_t)npad * 4);
  float* srowsg = (float*)alloc((size_t)npad * 4);
  float* cl2 = (float*)alloc(16);
  double* bsum = (double*)alloc((size_t)ntri * 8);
  int* counters = (int*)alloc(256);
  (void)ws_size; (void)n_in; (void)out_size;

  float* out      = (float*)d_out;
  float* out_sel0 = out + (size_t)S * CC;
  float* out_bal  = out + (size_t)S * CC + (size_t)S * E * 2;
  float* out_dist = out_bal + 1;

  k_route<<<S / 4, 256, 0, stream>>>(x, noise, Wr, i0, i1, g0, g1, out_sel0, selpart, counters);
  k_gpart<<<1024, 128, 0, stream>>>(x, i0, i1, g0, g1, gpart);
  k_gred<<<64, 256, 0, stream>>>(gpart, ei);
  k_layer<M, H1, true><<<(E * H1 + 3) / 4, 256, 0, stream>>>(ei, W1, b1, h1);
  k_layer<H1, H2, true><<<(E * H2 + 3) / 4, 256, 0, stream>>>(h1, W2, b2, h2);
  k_layer<H2, H3, true><<<(E * H3 + 3) / 4, 256, 0, stream>>>(h2, W3, b3, h3);
  k_layer<H3, CC, false><<<(E * CC + 3) / 4, 256, 0, stream>>>(h3, W4, b4, eo);
  k_gprep<<<1 + nrowblk, 256, 0, stream>>>(eo, selpart, idx1, idx2, i0, i1, g0, g1,
                                           G32, rowg, rowe, wpart, cpart, out_bal, ns, n, npad);
  k_mid<<<nrowblk, 256, 0, stream>>>(G32, wpart, cpart, rowg, rowe,
                                     srowg, srowA, srowe, srowsg, cl2, ns, n, npad, nrowblk);
  k_tail<<<ntri + (S * CC) / 512, 512, 0, stream>>>(eo, i0, i1, g0, g1, out, srowg, srowA,
                                                    srowe, srowsg, G32, cl2, bsum, out_dist,
                                                    ns, n, nt, ntri, counters);
}